// Round 1
// 497.838 us; speedup vs baseline: 1.0460x; 1.0460x over previous
//
#include <hip/hip_runtime.h>
#include <hip/hip_bf16.h>

// ---------------------------------------------------------------------------
// SparseCausalSelfAttention: B=2,T=2048,E=2048,NH=16,HS=128.
// I/O float32; internal bf16 MFMA, fp32 acc. Mask = fixed (t%2==0) interleave.
//
// ws plan (peak 96 MiB):
//   [ 0,48M) QKVall (B*T,6144) -> later Yb [0,16M), WPT_A [16,24M), WPT_B [24,32M)
//   [48,56M) XA ; [56,64M) XB  -> later Qb [48,64M)
//   [64,88M) WQT               -> later Kb [64,80M), Vtb [80,96M)
//
// GEMMs: 256x256 tile, BK=64, 8 waves (2Mx4N), 8-phase counted-vmcnt schedule
// (T2 swizzle + T3/T4 pipeline + T5 setprio + T1 XCD swizzle).
// ---------------------------------------------------------------------------

typedef __attribute__((ext_vector_type(8))) short v8s;   // 8 bf16 (4 VGPRs)
typedef __attribute__((ext_vector_type(4))) float v4f;   // MFMA accumulator

#define GL2LDS(gptr, lptr)                                              \
  __builtin_amdgcn_global_load_lds(                                     \
      (const __attribute__((address_space(1))) void*)(gptr),            \
      (__attribute__((address_space(3))) void*)(lptr), 16, 0, 0)

#define S_BARRIER() asm volatile("s_barrier" ::: "memory")

__device__ __forceinline__ float b2f(unsigned short u) {
  return __uint_as_float(((unsigned int)u) << 16);
}
__device__ __forceinline__ unsigned short f2bf(float f) {
  unsigned int u = __float_as_uint(f);
  u += 0x7fffu + ((u >> 16) & 1u);   // RNE
  return (unsigned short)(u >> 16);
}

// ---------------------------------------------------------------------------
// Both x streams -> bf16 in one launch (XA,XB contiguous in ws).
// ---------------------------------------------------------------------------
__global__ __launch_bounds__(256) void f32_to_bf16_2(
    const float4* __restrict__ a, const float4* __restrict__ b,
    uint2* __restrict__ out, int n4each) {
  int i = blockIdx.x * 256 + threadIdx.x;
  if (i >= 2 * n4each) return;
  float4 v = (i < n4each) ? a[i] : b[i - n4each];
  uint2 o;
  o.x = (unsigned int)f2bf(v.x) | ((unsigned int)f2bf(v.y) << 16);
  o.y = (unsigned int)f2bf(v.z) | ((unsigned int)f2bf(v.w) << 16);
  out[i] = o;
}

// ---------------------------------------------------------------------------
// Transpose f32 (R x C) -> bf16 (C x R); z selects (in0->out0)/(in1->out1).
// ---------------------------------------------------------------------------
__global__ __launch_bounds__(256) void transpose_f32_bf16(
    const float* __restrict__ in0, const float* __restrict__ in1,
    unsigned short* __restrict__ out0, unsigned short* __restrict__ out1,
    int R, int C) {
  const float* in = blockIdx.z ? in1 : in0;
  unsigned short* out = blockIdx.z ? out1 : out0;
  __shared__ unsigned short tile[64][65];
  const int bc = blockIdx.x * 64, br = blockIdx.y * 64;
  const int c  = threadIdx.x & 63;
  const int r0 = threadIdx.x >> 6;
  for (int r = r0; r < 64; r += 4)
    tile[r][c] = f2bf(in[(size_t)(br + r) * C + bc + c]);
  __syncthreads();
  for (int rr = r0; rr < 64; rr += 4)
    out[(size_t)(bc + rr) * R + br + c] = tile[c][rr];
}

// ---------------------------------------------------------------------------
// 256x256-tile GEMM helpers.
// ---------------------------------------------------------------------------
template <int MH, int NH>
__device__ __forceinline__ void mfma_quad(v4f (&acc)[8][4], const v8s (&a)[4][2],
                                          const v8s (&b)[4][2]) {
  __builtin_amdgcn_s_setprio(1);
#pragma unroll
  for (int ks = 0; ks < 2; ++ks)
#pragma unroll
    for (int i = 0; i < 4; ++i)
#pragma unroll
      for (int j = 0; j < 2; ++j)
        acc[MH * 4 + i][NH * 2 + j] = __builtin_amdgcn_mfma_f32_16x16x32_bf16(
            a[i][ks], b[NH * 2 + j][ks], acc[MH * 4 + i][NH * 2 + j], 0, 0, 0);
  __builtin_amdgcn_s_setprio(0);
}

__device__ __forceinline__ void read_a_half(const unsigned short* lds, int base,
                                            int mh, int r, int c0, int c1,
                                            v8s (&a)[4][2]) {
#pragma unroll
  for (int i = 0; i < 4; ++i) {
    const unsigned short* ap = lds + base + (mh * 64 + i * 16 + r) * 64;
    a[i][0] = *(const v8s*)(ap + c0);
    a[i][1] = *(const v8s*)(ap + c1);
  }
}

template <int NH>
__device__ __forceinline__ void read_b_half(const unsigned short* lds, int base,
                                            int brow, int r, int c0, int c1,
                                            v8s (&b)[4][2]) {
#pragma unroll
  for (int j = 0; j < 2; ++j) {
    const unsigned short* bp = lds + base + (brow + (NH * 2 + j) * 16 + r) * 64;
    b[NH * 2 + j][0] = *(const v8s*)(bp + c0);
    b[NH * 2 + j][1] = *(const v8s*)(bp + c1);
  }
}

// ---------------------------------------------------------------------------
// gemm256: C[M,N] = A[M,K] @ BT[N,K]^T, bf16 in / (bf16|f32) out.
//   GATHER: 0 = A rows linear; 1 = proj gather (token rows, par = stream).
//   OSCAT : 0 = f32 linear out (+par*M*N); 1/2 = bf16 out scattered to
//           interleaved token rows (even/odd).
//
// Schedule: 8 LDS half-tile regions of 16KB (ring, order per tile:
// {B0,B1,A0,A1}); phases 1-4 compute K-tile t (regions 0-3), 5-8 tile t+1
// (regions 4-7). Each phase stages ONE half-tile (2x gl_lds/thread) into the
// region freed >=1 barrier earlier; vmcnt(4) checkpoints at phases 4/8 keep
// the newest 2 half-tiles in flight (never drain to 0 mid-loop; last iter
// drains fully since its prefetches are skipped). ds_read swizzle: 16B slot
// ^= (row&7), matched by pre-swizzled gl_lds global source (linear LDS dst).
// Requires: M%256==0, N%256==0, K%128==0, grid.x%8==0.
// ---------------------------------------------------------------------------
template <int GATHER, int OSCAT>
__global__ __launch_bounds__(512, 2) void gemm256(
    const unsigned short* __restrict__ A,
    const unsigned short* __restrict__ BT0,
    const unsigned short* __restrict__ BT1,
    void* __restrict__ Cout, int M, int N, int K, int NBN) {
  __shared__ __align__(16) unsigned short lds[65536];   // 128 KiB
  const int tid = threadIdx.x;
  const int par = blockIdx.y;
  const unsigned short* __restrict__ BT = par ? BT1 : BT0;

  int wg = blockIdx.x;
  const int cpx = gridDim.x >> 3;            // bijective XCD swizzle (x%8==0)
  wg = (wg & 7) * cpx + (wg >> 3);
  const int m0 = (wg / NBN) * 256, n0 = (wg % NBN) * 256;

  const int w = tid >> 6, lane = tid & 63;
  const int wm = w >> 2, wn = w & 3;         // wave tile: rows wm*128, cols wn*64
  const int r = lane & 15, q = lane >> 4;
  const int rs = r & 7;
  const int c0 = ((q ^ rs) << 3);            // swizzled ushort col, ks=0
  const int c1 = (((4 + q) ^ rs) << 3);      // ks=1
  const int brow = (wn & 1) << 6;
  const int AbaseE = (2 + wm) * 8192, BbaseE = (wn >> 1) * 8192;
  const int AbaseO = (6 + wm) * 8192, BbaseO = (4 + (wn >> 1)) * 8192;

  const int sr0 = tid >> 3, sslot = tid & 7; // staging coords
  const int NT = K >> 6, NIT = NT >> 1;

  auto stageB = [&](int p, int tt) {
    unsigned short* dst = &lds[(((tt << 2) + p) & 7) * 8192 + w * 512];
#pragma unroll
    for (int cc = 0; cc < 2; ++cc) {
      const int row = sr0 + cc * 64;
      const int g = ((sslot ^ (row & 7)) << 3);
      GL2LDS(BT + (size_t)(n0 + p * 128 + row) * K + tt * 64 + g, dst + cc * 4096);
    }
  };
  auto stageA = [&](int p, int tt) {
    unsigned short* dst = &lds[(((tt << 2) + 2 + p) & 7) * 8192 + w * 512];
#pragma unroll
    for (int cc = 0; cc < 2; ++cc) {
      const int row = sr0 + cc * 64;
      const int g = ((sslot ^ (row & 7)) << 3);
      int ar = m0 + p * 128 + row;
      if constexpr (GATHER) ar = ((ar >> 10) << 11) + ((ar & 1023) << 1) + par;
      GL2LDS(A + (size_t)ar * K + tt * 64 + g, dst + cc * 4096);
    }
  };

  v4f acc[8][4] = {};
  v8s a[4][2], b[4][2];

  // prologue: h0..h5 = B0(0) B1(0) A0(0) A1(0) B0(1) B1(1)
  stageB(0, 0); stageB(1, 0); stageA(0, 0); stageA(1, 0);
  asm volatile("" ::: "memory");             // pin issue order at vmcnt cut
  stageB(0, 1); stageB(1, 1);
  asm volatile("s_waitcnt vmcnt(4)" ::: "memory");   // tile 0 resident
  S_BARRIER();

  for (int it = 0; it < NIT; ++it) {
    const int t = it << 1;
    const bool more = (it + 1 < NIT);

    // ---- phase 1: A-lo + B-lo reads (12x b128), stage A0(t+1) -> region 6
    read_a_half(lds, AbaseE, 0, r, c0, c1, a);
    read_b_half<0>(lds, BbaseE, brow, r, c0, c1, b);
    stageA(0, t + 1);
    S_BARRIER();
    mfma_quad<0, 0>(acc, a, b);
    S_BARRIER();
    // ---- phase 2: B-hi reads, stage A1(t+1) -> region 7
    read_b_half<1>(lds, BbaseE, brow, r, c0, c1, b);
    stageA(1, t + 1);
    S_BARRIER();
    mfma_quad<0, 1>(acc, a, b);
    S_BARRIER();
    // ---- phase 3: A-hi reads, stage B0(t+2) -> region 0 (B(t) reads done ph2)
    read_a_half(lds, AbaseE, 1, r, c0, c1, a);
    if (more) stageB(0, t + 2);
    S_BARRIER();
    mfma_quad<1, 0>(acc, a, b);
    S_BARRIER();
    // ---- phase 4: stage B1(t+2) -> region 1; checkpoint tile t+1
    if (more) stageB(1, t + 2);
    S_BARRIER();
    mfma_quad<1, 1>(acc, a, b);
    if (more) { asm volatile("s_waitcnt vmcnt(4)" ::: "memory"); }
    else      { asm volatile("s_waitcnt vmcnt(0)" ::: "memory"); }
    S_BARRIER();

    // ---- phase 5 (tile t+1): stage A0(t+2) -> region 2 (A(t) reads done ph3)
    read_a_half(lds, AbaseO, 0, r, c0, c1, a);
    read_b_half<0>(lds, BbaseO, brow, r, c0, c1, b);
    if (more) stageA(0, t + 2);
    S_BARRIER();
    mfma_quad<0, 0>(acc, a, b);
    S_BARRIER();
    // ---- phase 6: stage A1(t+2) -> region 3
    read_b_half<1>(lds, BbaseO, brow, r, c0, c1, b);
    if (more) stageA(1, t + 2);
    S_BARRIER();
    mfma_quad<0, 1>(acc, a, b);
    S_BARRIER();
    // ---- phase 7: stage B0(t+3) -> region 4 (B(t+1) reads done ph6)
    read_a_half(lds, AbaseO, 1, r, c0, c1, a);
    if (more) stageB(0, t + 3);
    S_BARRIER();
    mfma_quad<1, 0>(acc, a, b);
    S_BARRIER();
    // ---- phase 8: stage B1(t+3) -> region 5; checkpoint tile t+2
    if (more) stageB(1, t + 3);
    S_BARRIER();
    mfma_quad<1, 1>(acc, a, b);
    if (more) { asm volatile("s_waitcnt vmcnt(4)" ::: "memory"); }
    S_BARRIER();
  }

  // ---- epilogue
  float* Cf = (float*)Cout + (size_t)par * M * N;
  unsigned short* Cb = (unsigned short*)Cout;
#pragma unroll
  for (int tm = 0; tm < 8; ++tm) {
    const int rowm = m0 + wm * 128 + tm * 16 + q * 4;
#pragma unroll
    for (int tn = 0; tn < 4; ++tn) {
      const int col = n0 + wn * 64 + tn * 16 + r;
#pragma unroll
      for (int p = 0; p < 4; ++p) {
        if constexpr (OSCAT == 0) {
          Cf[(size_t)(rowm + p) * N + col] = acc[tm][tn][p];
        } else {
          const int ar = rowm + p;
          const int orow = ((ar >> 10) << 11) + ((ar & 1023) << 1) + (OSCAT - 1);
          Cb[(size_t)orow * N + col] = f2bf(acc[tm][tn][p]);
        }
      }
    }
  }
}

// ---------------------------------------------------------------------------
// QKVall -> Q,K (B,NH,T,HS) with RoPE. One block per token.
// ---------------------------------------------------------------------------
__global__ __launch_bounds__(256) void scatter_rope(
    const unsigned short* __restrict__ qkv,
    const float* __restrict__ cosb, const float* __restrict__ sinb,
    unsigned short* __restrict__ Q, unsigned short* __restrict__ K) {
  const int token = blockIdx.x;          // b*2048 + t
  const int b = token >> 11, t = token & 2047;
  const unsigned short* src = qkv + (size_t)token * 6144;
  for (int i = threadIdx.x; i < 2048; i += 256) {
    const int d = i & 127, h = i >> 7;
    const float cv = cosb[t * 128 + d];
    const float sv = sinb[t * 128 + d];
    const int   mate = (d < 64) ? i + 64 : i - 64;
    const float sgn  = (d < 64) ? -1.f : 1.f;
    const float qv = b2f(src[i]),        qm = b2f(src[mate]) * sgn;
    const float kv = b2f(src[2048 + i]), km = b2f(src[2048 + mate]) * sgn;
    const size_t off = ((size_t)(b * 16 + h) * 2048 + t) * 128 + d;
    Q[off] = f2bf(qv * cv + qm * sv);
    K[off] = f2bf(kv * cv + km * sv);
  }
}

// ---------------------------------------------------------------------------
// V part of QKVall -> Vt (B*NH, HS, T) via LDS-tiled transpose.
// ---------------------------------------------------------------------------
__global__ __launch_bounds__(256) void transpose_v(
    const unsigned short* __restrict__ qkv, unsigned short* __restrict__ Vt) {
  __shared__ unsigned short tile[128][129];
  const int bh = blockIdx.x >> 4, tt = blockIdx.x & 15;
  const int b = bh >> 4, h = bh & 15;
  const int tid = threadIdx.x;
  const int d0 = tid & 127, t0 = tid >> 7;
#pragma unroll 4
  for (int i = 0; i < 64; ++i) {
    int tl = i * 2 + t0;
    tile[tl][d0] =
        qkv[((size_t)(b * 2048 + tt * 128 + tl)) * 6144 + 4096 + h * 128 + d0];
  }
  __syncthreads();
#pragma unroll 4
  for (int i = 0; i < 64; ++i) {
    int dd = i * 2 + t0;
    Vt[((size_t)(bh * 128 + dd)) * 2048 + tt * 128 + d0] = tile[d0][dd];
  }
}

// ---------------------------------------------------------------------------
// Flash attention, BQ=64, BK=64, 4 waves, balanced q-tile pairing:
// block pr handles q-tiles (31-pr) then (pr): (32-pr) + (pr+1) = 33 k-tiles
// for every block. Grid 512 = 2 blocks/CU, LDS 48KB. Each wave owns 16 q-rows.
// ---------------------------------------------------------------------------
#define SIG 0.1275174038536989f   // (1/sqrt(128)) * log2(e)

__global__ __launch_bounds__(256, 2) void attn_flash(
    const unsigned short* __restrict__ Q, const unsigned short* __restrict__ K,
    const unsigned short* __restrict__ Vt, unsigned short* __restrict__ Y) {
  __shared__ __align__(16) unsigned short Ks[64 * 128];
  __shared__ __align__(16) unsigned short Vs[128 * 64];
  __shared__ __align__(16) unsigned short QP[64 * 128];  // Q tile, then P (stride 72)

  const int bh = blockIdx.x >> 4, pr = blockIdx.x & 15;
  const int tid = threadIdx.x, w = tid >> 6, lane = tid & 63;
  const int r = lane & 15, q = lane >> 4;
  const int b = bh >> 4, h = bh & 15;
  const size_t kbase = (size_t)bh * 2048 * 128;
  const size_t vbase = (size_t)bh * 128 * 2048;

  for (int ph = 0; ph < 2; ++ph) {
    const int qt = ph ? pr : (31 - pr);

    // ---- stage Q tile (64 rows x 128d), swizzled; wave stages/reads own rows
    const size_t qbase = ((size_t)bh * 2048 + qt * 64) * 128;
#pragma unroll
    for (int i = 0; i < 4; ++i) {
      const int rowl = w * 16 + i * 4 + q;
      const int g = r ^ (rowl & 15);
      GL2LDS(Q + qbase + (size_t)rowl * 128 + g * 8, &QP[(w * 16 + i * 4) * 128]);
    }
    __builtin_amdgcn_s_waitcnt(0);
    v8s qf[4];
#pragma unroll
    for (int ki = 0; ki < 4; ++ki) {
      const int rowl = w * 16 + r;
      const int c = (ki * 4 + q) ^ r;
      qf[ki] = *(const v8s*)&QP[rowl * 128 + c * 8];
    }
    __syncthreads();   // QP now free for P

    float mrun[4], lrun[4];
    v4f O[8] = {};
#pragma unroll
    for (int p = 0; p < 4; ++p) { mrun[p] = -3.0e38f; lrun[p] = 0.f; }

    const int nkt = qt + 1;
    for (int kt = 0; kt < nkt; ++kt) {
      // ---- stage K-tile (64 keys x 128d) and Vt-tile (128d x 64 keys)
#pragma unroll
      for (int i = 0; i < 4; ++i) {
        const int key = w * 16 + i * 4 + q;
        const int g = r ^ (key & 15);
        GL2LDS(K + kbase + ((size_t)kt * 64 + key) * 128 + g * 8,
               &Ks[(w * 16 + i * 4) * 128]);
      }
      const int vrow = lane >> 3, pc = lane & 7;
#pragma unroll
      for (int i = 0; i < 4; ++i) {
        const int d = w * 32 + i * 8 + vrow;
        const int g = pc ^ (d & 7);
        GL2LDS(Vt + vbase + (size_t)d * 2048 + kt * 64 + g * 8,
               &Vs[(w * 32 + i * 8) * 64]);
      }
      __builtin_amdgcn_s_waitcnt(0);
      __syncthreads();

      // ---- S = Q K^T  (rows: w*16 + q*4+p, cols: tn*16+r)
      v4f S[4] = {};
#pragma unroll
      for (int ki = 0; ki < 4; ++ki) {
        v8s kf[4];
#pragma unroll
        for (int tn = 0; tn < 4; ++tn) {
          const int key = tn * 16 + r;
          const int c = (ki * 4 + q) ^ r;
          kf[tn] = *(const v8s*)&Ks[key * 128 + c * 8];
        }
#pragma unroll
        for (int tn = 0; tn < 4; ++tn)
          S[tn] = __builtin_amdgcn_mfma_f32_16x16x32_bf16(
              qf[ki], kf[tn], S[tn], 0, 0, 0);
      }

      // ---- causal mask (diagonal tile only: kt == qt)
      if (kt == qt) {
#pragma unroll
        for (int tn = 0; tn < 4; ++tn)
#pragma unroll
          for (int p = 0; p < 4; ++p) {
            const int tq = w * 16 + q * 4 + p;        // local q-row
            const int kg = tn * 16 + r;               // local key
            if (kg > tq) S[tn][p] = -3.0e38f;
          }
      }

      // ---- online softmax (base-2), P into S regs, rescale O
#pragma unroll
      for (int p = 0; p < 4; ++p) {
        float mx = fmaxf(fmaxf(S[0][p], S[1][p]), fmaxf(S[2][p], S[3][p]));
#pragma unroll
        for (int o = 1; o < 16; o <<= 1) mx = fmaxf(mx, __shfl_xor(mx, o, 64));
        const float mnew = fmaxf(mrun[p], mx);
        const float alpha = exp2f((mrun[p] - mnew) * SIG);
        mrun[p] = mnew;
        float sum = 0.f;
#pragma unroll
        for (int tn = 0; tn < 4; ++tn) {
          const float pv = exp2f((S[tn][p] - mnew) * SIG);
          S[tn][p] = pv;
          sum += pv;
        }
#pragma unroll
        for (int o = 1; o < 16; o <<= 1) sum += __shfl_xor(sum, o, 64);
        lrun[p] = lrun[p] * alpha + sum;
#pragma unroll
        for (int tn = 0; tn < 8; ++tn) O[tn][p] *= alpha;
      }

      // ---- P (bf16) to LDS, stride 72; own rows only
#pragma unroll
      for (int tn = 0; tn < 4; ++tn)
#pragma unroll
        for (int p = 0; p < 4; ++p) {
          const int m = w * 16 + q * 4 + p;
          QP[m * 72 + tn * 16 + r] = f2bf(S[tn][p]);
        }

      // ---- O += P V   (A=P rows, B=Vt rows)
#pragma unroll
      for (int ki = 0; ki < 2; ++ki) {
        v8s pf, vf[8];
        const int m = w * 16 + r;
        pf = *(const v8s*)&QP[m * 72 + (ki * 4 + q) * 8];
#pragma unroll
        for (int tn = 0; tn < 8; ++tn) {
          const int d = tn * 16 + r;
          const int c = (ki * 4 + q) ^ (d & 7);
          vf[tn] = *(const v8s*)&Vs[d * 64 + c * 8];
        }
#pragma unroll
        for (int tn = 0; tn < 8; ++tn)
          O[tn] = __builtin_amdgcn_mfma_f32_16x16x32_bf16(
              pf, vf[tn], O[tn], 0, 0, 0);
      }
      __syncthreads();   // protect Ks/Vs/QP before next stage
    }

    // ---- epilogue: O/l -> Y[(b*T+t)][h*128+d]
#pragma unroll
    for (int p = 0; p < 4; ++p) {
      const float inv = 1.0f / lrun[p];
      const int t = qt * 64 + w * 16 + q * 4 + p;
#pragma unroll
      for (int tn = 0; tn < 8; ++tn)
        Y[((size_t)(b * 2048 + t)) * 2048 + h * 128 + tn * 16 + r] =
            f2bf(O[tn][p] * inv);
    }
  }
}

// ---------------------------------------------------------------------------
// Launch
// ---------------------------------------------------------------------------
extern "C" void kernel_launch(void* const* d_in, const int* in_sizes, int n_in,
                              void* d_out, int out_size, void* d_ws, size_t ws_size,
                              hipStream_t stream) {
  const float* x_a   = (const float*)d_in[0];
  const float* x_b   = (const float*)d_in[1];
  const float* cosb  = (const float*)d_in[2];
  const float* sinb  = (const float*)d_in[3];
  const float* Wqkv_a  = (const float*)d_in[5];
  const float* Wqkv_b  = (const float*)d_in[6];
  const float* Wproj_a = (const float*)d_in[7];
  const float* Wproj_b = (const float*)d_in[8];
  float* out = (float*)d_out;

  if (ws_size < 100663296u) return;

  char* ws = (char*)d_ws;
  unsigned short* QKVall = (unsigned short*)(ws);                // [0,48M)
  unsigned short* XA     = (unsigned short*)(ws + 50331648);     // [48,56M)
  unsigned short* WQT    = (unsigned short*)(ws + 67108864);     // [64,88M)
  unsigned short* Qb     = (unsigned short*)(ws + 50331648);     // [48,64M)
  unsigned short* Kb     = (unsigned short*)(ws + 67108864);     // [64,80M)
  unsigned short* Vtb    = (unsigned short*)(ws + 83886080);     // [80,96M)
  unsigned short* Yb     = (unsigned short*)(ws);                // [0,16M)
  unsigned short* WPT_A  = (unsigned short*)(ws + 16777216);     // [16,24M)
  unsigned short* WPT_B  = (unsigned short*)(ws + 25165824);     // [24,32M)

  // phase 1: conversions + qkv GEMMs (token-scattered output rows)
  hipLaunchKernelGGL(f32_to_bf16_2, dim3(8192), dim3(256), 0, stream,
                     (const float4*)x_a, (const float4*)x_b, (uint2*)XA, 1048576);
  hipLaunchKernelGGL(transpose_f32_bf16, dim3(96, 32, 1), dim3(256), 0, stream,
                     Wqkv_a, Wqkv_a, WQT, WQT, 2048, 6144);
  hipLaunchKernelGGL((gemm256<0, 1>), dim3(192, 1), dim3(512), 0, stream,
                     XA, WQT, WQT, QKVall, 2048, 6144, 2048, 24);
  hipLaunchKernelGGL(transpose_f32_bf16, dim3(96, 32, 1), dim3(256), 0, stream,
                     Wqkv_b, Wqkv_b, WQT, WQT, 2048, 6144);
  hipLaunchKernelGGL((gemm256<0, 2>), dim3(192, 1), dim3(512), 0, stream,
                     XA + (size_t)4194304, WQT, WQT, QKVall, 2048, 6144, 2048, 24);

  // phase 2: RoPE Q/K + V transpose (both read QKVall)
  hipLaunchKernelGGL(scatter_rope, dim3(4096), dim3(256), 0, stream,
                     QKVall, cosb, sinb, Qb, Kb);
  hipLaunchKernelGGL(transpose_v, dim3(512), dim3(256), 0, stream,
                     QKVall, Vtb);

  // phase 3: both Wproj transposes in one launch (dead QKVall region)
  hipLaunchKernelGGL(transpose_f32_bf16, dim3(32, 32, 2), dim3(256), 0, stream,
                     Wproj_a, Wproj_b, WPT_A, WPT_B, 2048, 2048);

  // phase 4: flash attention -> Yb (balanced q-tile pairs)
  hipLaunchKernelGGL(attn_flash, dim3(512), dim3(256), 0, stream,
                     Qb, Kb, Vtb, Yb);

  // phase 5: both output projections in one launch (y = stream parity)
  hipLaunchKernelGGL((gemm256<1, 0>), dim3(64, 2), dim3(512), 0, stream,
                     Yb, WPT_A, WPT_B, out, 2048, 2048, 2048, 8);
}

// Round 2
// 495.947 us; speedup vs baseline: 1.0500x; 1.0038x over previous
//
#include <hip/hip_runtime.h>
#include <hip/hip_bf16.h>

// ---------------------------------------------------------------------------
// SparseCausalSelfAttention: B=2,T=2048,E=2048,NH=16,HS=128.
// I/O float32; internal bf16 MFMA, fp32 acc. Mask = fixed (t%2==0) interleave.
//
// ws plan (peak 96 MiB):
//   [ 0,48M) QKVall (B*T,6144) -> later Yb [0,16M), WPT_A [16,24M), WPT_B [24,32M)
//   [48,56M) XA ; [56,64M) XB  -> later Qb [48,64M)
//   [64,88M) WQT               -> later Kb [64,80M), Vtb [80,96M)
//
// GEMMs: 256x256 tile, BK=64, 8 waves (2Mx4N), 8-phase counted-vmcnt schedule
// (T2 swizzle + T3/T4 pipeline + T5 setprio + T1 XCD swizzle).
// Attn: double-buffered K/V, counted vmcnt(8) prefetch, raw s_barrier only,
// Q fragments direct from global, XCD-local (b,h) block mapping.
// ---------------------------------------------------------------------------

typedef __attribute__((ext_vector_type(8))) short v8s;   // 8 bf16 (4 VGPRs)
typedef __attribute__((ext_vector_type(4))) float v4f;   // MFMA accumulator

#define GL2LDS(gptr, lptr)                                              \
  __builtin_amdgcn_global_load_lds(                                     \
      (const __attribute__((address_space(1))) void*)(gptr),            \
      (__attribute__((address_space(3))) void*)(lptr), 16, 0, 0)

#define S_BARRIER() asm volatile("s_barrier" ::: "memory")

__device__ __forceinline__ float b2f(unsigned short u) {
  return __uint_as_float(((unsigned int)u) << 16);
}
__device__ __forceinline__ unsigned short f2bf(float f) {
  unsigned int u = __float_as_uint(f);
  u += 0x7fffu + ((u >> 16) & 1u);   // RNE
  return (unsigned short)(u >> 16);
}

// ---------------------------------------------------------------------------
// Both x streams -> bf16 in one launch (XA,XB contiguous in ws).
// ---------------------------------------------------------------------------
__global__ __launch_bounds__(256) void f32_to_bf16_2(
    const float4* __restrict__ a, const float4* __restrict__ b,
    uint2* __restrict__ out, int n4each) {
  int i = blockIdx.x * 256 + threadIdx.x;
  if (i >= 2 * n4each) return;
  float4 v = (i < n4each) ? a[i] : b[i - n4each];
  uint2 o;
  o.x = (unsigned int)f2bf(v.x) | ((unsigned int)f2bf(v.y) << 16);
  o.y = (unsigned int)f2bf(v.z) | ((unsigned int)f2bf(v.w) << 16);
  out[i] = o;
}

// ---------------------------------------------------------------------------
// Transpose f32 (R x C) -> bf16 (C x R); z selects (in0->out0)/(in1->out1).
// ---------------------------------------------------------------------------
__global__ __launch_bounds__(256) void transpose_f32_bf16(
    const float* __restrict__ in0, const float* __restrict__ in1,
    unsigned short* __restrict__ out0, unsigned short* __restrict__ out1,
    int R, int C) {
  const float* in = blockIdx.z ? in1 : in0;
  unsigned short* out = blockIdx.z ? out1 : out0;
  __shared__ unsigned short tile[64][65];
  const int bc = blockIdx.x * 64, br = blockIdx.y * 64;
  const int c  = threadIdx.x & 63;
  const int r0 = threadIdx.x >> 6;
  for (int r = r0; r < 64; r += 4)
    tile[r][c] = f2bf(in[(size_t)(br + r) * C + bc + c]);
  __syncthreads();
  for (int rr = r0; rr < 64; rr += 4)
    out[(size_t)(bc + rr) * R + br + c] = tile[c][rr];
}

// ---------------------------------------------------------------------------
// 256x256-tile GEMM helpers.
// ---------------------------------------------------------------------------
template <int MH, int NH>
__device__ __forceinline__ void mfma_quad(v4f (&acc)[8][4], const v8s (&a)[4][2],
                                          const v8s (&b)[4][2]) {
  __builtin_amdgcn_s_setprio(1);
#pragma unroll
  for (int ks = 0; ks < 2; ++ks)
#pragma unroll
    for (int i = 0; i < 4; ++i)
#pragma unroll
      for (int j = 0; j < 2; ++j)
        acc[MH * 4 + i][NH * 2 + j] = __builtin_amdgcn_mfma_f32_16x16x32_bf16(
            a[i][ks], b[NH * 2 + j][ks], acc[MH * 4 + i][NH * 2 + j], 0, 0, 0);
  __builtin_amdgcn_s_setprio(0);
}

__device__ __forceinline__ void read_a_half(const unsigned short* lds, int base,
                                            int mh, int r, int c0, int c1,
                                            v8s (&a)[4][2]) {
#pragma unroll
  for (int i = 0; i < 4; ++i) {
    const unsigned short* ap = lds + base + (mh * 64 + i * 16 + r) * 64;
    a[i][0] = *(const v8s*)(ap + c0);
    a[i][1] = *(const v8s*)(ap + c1);
  }
}

template <int NH>
__device__ __forceinline__ void read_b_half(const unsigned short* lds, int base,
                                            int brow, int r, int c0, int c1,
                                            v8s (&b)[4][2]) {
#pragma unroll
  for (int j = 0; j < 2; ++j) {
    const unsigned short* bp = lds + base + (brow + (NH * 2 + j) * 16 + r) * 64;
    b[NH * 2 + j][0] = *(const v8s*)(bp + c0);
    b[NH * 2 + j][1] = *(const v8s*)(bp + c1);
  }
}

// ---------------------------------------------------------------------------
// gemm256: C[M,N] = A[M,K] @ BT[N,K]^T, bf16 in / (bf16|f32) out.
//   GATHER: 0 = A rows linear; 1 = proj gather (token rows, par = stream).
//   OSCAT : 0 = f32 linear out (+par*M*N); 1/2 = bf16 out scattered to
//           interleaved token rows (even/odd).
//
// Schedule: 8 LDS half-tile regions of 16KB (ring, order per tile:
// {B0,B1,A0,A1}); phases 1-4 compute K-tile t (regions 0-3), 5-8 tile t+1
// (regions 4-7). Each phase stages ONE half-tile (2x gl_lds/thread) into the
// region freed >=1 barrier earlier; vmcnt(4) checkpoints at phases 4/8 keep
// the newest 2 half-tiles in flight (never drain to 0 mid-loop; last iter
// drains fully since its prefetches are skipped). ds_read swizzle: 16B slot
// ^= (row&7), matched by pre-swizzled gl_lds global source (linear LDS dst).
// Requires: M%256==0, N%256==0, K%128==0, grid.x%8==0.
// ---------------------------------------------------------------------------
template <int GATHER, int OSCAT>
__global__ __launch_bounds__(512, 2) void gemm256(
    const unsigned short* __restrict__ A,
    const unsigned short* __restrict__ BT0,
    const unsigned short* __restrict__ BT1,
    void* __restrict__ Cout, int M, int N, int K, int NBN) {
  __shared__ __align__(16) unsigned short lds[65536];   // 128 KiB
  const int tid = threadIdx.x;
  const int par = blockIdx.y;
  const unsigned short* __restrict__ BT = par ? BT1 : BT0;

  int wg = blockIdx.x;
  const int cpx = gridDim.x >> 3;            // bijective XCD swizzle (x%8==0)
  wg = (wg & 7) * cpx + (wg >> 3);
  const int m0 = (wg / NBN) * 256, n0 = (wg % NBN) * 256;

  const int w = tid >> 6, lane = tid & 63;
  const int wm = w >> 2, wn = w & 3;         // wave tile: rows wm*128, cols wn*64
  const int r = lane & 15, q = lane >> 4;
  const int rs = r & 7;
  const int c0 = ((q ^ rs) << 3);            // swizzled ushort col, ks=0
  const int c1 = (((4 + q) ^ rs) << 3);      // ks=1
  const int brow = (wn & 1) << 6;
  const int AbaseE = (2 + wm) * 8192, BbaseE = (wn >> 1) * 8192;
  const int AbaseO = (6 + wm) * 8192, BbaseO = (4 + (wn >> 1)) * 8192;

  const int sr0 = tid >> 3, sslot = tid & 7; // staging coords
  const int NT = K >> 6, NIT = NT >> 1;

  auto stageB = [&](int p, int tt) {
    unsigned short* dst = &lds[(((tt << 2) + p) & 7) * 8192 + w * 512];
#pragma unroll
    for (int cc = 0; cc < 2; ++cc) {
      const int row = sr0 + cc * 64;
      const int g = ((sslot ^ (row & 7)) << 3);
      GL2LDS(BT + (size_t)(n0 + p * 128 + row) * K + tt * 64 + g, dst + cc * 4096);
    }
  };
  auto stageA = [&](int p, int tt) {
    unsigned short* dst = &lds[(((tt << 2) + 2 + p) & 7) * 8192 + w * 512];
#pragma unroll
    for (int cc = 0; cc < 2; ++cc) {
      const int row = sr0 + cc * 64;
      const int g = ((sslot ^ (row & 7)) << 3);
      int ar = m0 + p * 128 + row;
      if constexpr (GATHER) ar = ((ar >> 10) << 11) + ((ar & 1023) << 1) + par;
      GL2LDS(A + (size_t)ar * K + tt * 64 + g, dst + cc * 4096);
    }
  };

  v4f acc[8][4] = {};
  v8s a[4][2], b[4][2];

  // prologue: h0..h5 = B0(0) B1(0) A0(0) A1(0) B0(1) B1(1)
  stageB(0, 0); stageB(1, 0); stageA(0, 0); stageA(1, 0);
  asm volatile("" ::: "memory");             // pin issue order at vmcnt cut
  stageB(0, 1); stageB(1, 1);
  asm volatile("s_waitcnt vmcnt(4)" ::: "memory");   // tile 0 resident
  S_BARRIER();

  for (int it = 0; it < NIT; ++it) {
    const int t = it << 1;
    const bool more = (it + 1 < NIT);

    // ---- phase 1: A-lo + B-lo reads (12x b128), stage A0(t+1) -> region 6
    read_a_half(lds, AbaseE, 0, r, c0, c1, a);
    read_b_half<0>(lds, BbaseE, brow, r, c0, c1, b);
    stageA(0, t + 1);
    S_BARRIER();
    mfma_quad<0, 0>(acc, a, b);
    S_BARRIER();
    // ---- phase 2: B-hi reads, stage A1(t+1) -> region 7
    read_b_half<1>(lds, BbaseE, brow, r, c0, c1, b);
    stageA(1, t + 1);
    S_BARRIER();
    mfma_quad<0, 1>(acc, a, b);
    S_BARRIER();
    // ---- phase 3: A-hi reads, stage B0(t+2) -> region 0 (B(t) reads done ph2)
    read_a_half(lds, AbaseE, 1, r, c0, c1, a);
    if (more) stageB(0, t + 2);
    S_BARRIER();
    mfma_quad<1, 0>(acc, a, b);
    S_BARRIER();
    // ---- phase 4: stage B1(t+2) -> region 1; checkpoint tile t+1
    if (more) stageB(1, t + 2);
    S_BARRIER();
    mfma_quad<1, 1>(acc, a, b);
    if (more) { asm volatile("s_waitcnt vmcnt(4)" ::: "memory"); }
    else      { asm volatile("s_waitcnt vmcnt(0)" ::: "memory"); }
    S_BARRIER();

    // ---- phase 5 (tile t+1): stage A0(t+2) -> region 2 (A(t) reads done ph3)
    read_a_half(lds, AbaseO, 0, r, c0, c1, a);
    read_b_half<0>(lds, BbaseO, brow, r, c0, c1, b);
    if (more) stageA(0, t + 2);
    S_BARRIER();
    mfma_quad<0, 0>(acc, a, b);
    S_BARRIER();
    // ---- phase 6: stage A1(t+2) -> region 3
    read_b_half<1>(lds, BbaseO, brow, r, c0, c1, b);
    if (more) stageA(1, t + 2);
    S_BARRIER();
    mfma_quad<0, 1>(acc, a, b);
    S_BARRIER();
    // ---- phase 7: stage B0(t+3) -> region 4 (B(t+1) reads done ph6)
    read_a_half(lds, AbaseO, 1, r, c0, c1, a);
    if (more) stageB(0, t + 3);
    S_BARRIER();
    mfma_quad<1, 0>(acc, a, b);
    S_BARRIER();
    // ---- phase 8: stage B1(t+3) -> region 5; checkpoint tile t+2
    if (more) stageB(1, t + 3);
    S_BARRIER();
    mfma_quad<1, 1>(acc, a, b);
    if (more) { asm volatile("s_waitcnt vmcnt(4)" ::: "memory"); }
    S_BARRIER();
  }

  // ---- epilogue
  float* Cf = (float*)Cout + (size_t)par * M * N;
  unsigned short* Cb = (unsigned short*)Cout;
#pragma unroll
  for (int tm = 0; tm < 8; ++tm) {
    const int rowm = m0 + wm * 128 + tm * 16 + q * 4;
#pragma unroll
    for (int tn = 0; tn < 4; ++tn) {
      const int col = n0 + wn * 64 + tn * 16 + r;
#pragma unroll
      for (int p = 0; p < 4; ++p) {
        if constexpr (OSCAT == 0) {
          Cf[(size_t)(rowm + p) * N + col] = acc[tm][tn][p];
        } else {
          const int ar = rowm + p;
          const int orow = ((ar >> 10) << 11) + ((ar & 1023) << 1) + (OSCAT - 1);
          Cb[(size_t)orow * N + col] = f2bf(acc[tm][tn][p]);
        }
      }
    }
  }
}

// ---------------------------------------------------------------------------
// QKVall -> Q,K (B,NH,T,HS) with RoPE. One block per token.
// ---------------------------------------------------------------------------
__global__ __launch_bounds__(256) void scatter_rope(
    const unsigned short* __restrict__ qkv,
    const float* __restrict__ cosb, const float* __restrict__ sinb,
    unsigned short* __restrict__ Q, unsigned short* __restrict__ K) {
  const int token = blockIdx.x;          // b*2048 + t
  const int b = token >> 11, t = token & 2047;
  const unsigned short* src = qkv + (size_t)token * 6144;
  for (int i = threadIdx.x; i < 2048; i += 256) {
    const int d = i & 127, h = i >> 7;
    const float cv = cosb[t * 128 + d];
    const float sv = sinb[t * 128 + d];
    const int   mate = (d < 64) ? i + 64 : i - 64;
    const float sgn  = (d < 64) ? -1.f : 1.f;
    const float qv = b2f(src[i]),        qm = b2f(src[mate]) * sgn;
    const float kv = b2f(src[2048 + i]), km = b2f(src[2048 + mate]) * sgn;
    const size_t off = ((size_t)(b * 16 + h) * 2048 + t) * 128 + d;
    Q[off] = f2bf(qv * cv + qm * sv);
    K[off] = f2bf(kv * cv + km * sv);
  }
}

// ---------------------------------------------------------------------------
// V part of QKVall -> Vt (B*NH, HS, T) via LDS-tiled transpose.
// ---------------------------------------------------------------------------
__global__ __launch_bounds__(256) void transpose_v(
    const unsigned short* __restrict__ qkv, unsigned short* __restrict__ Vt) {
  __shared__ unsigned short tile[128][129];
  const int bh = blockIdx.x >> 4, tt = blockIdx.x & 15;
  const int b = bh >> 4, h = bh & 15;
  const int tid = threadIdx.x;
  const int d0 = tid & 127, t0 = tid >> 7;
#pragma unroll 4
  for (int i = 0; i < 64; ++i) {
    int tl = i * 2 + t0;
    tile[tl][d0] =
        qkv[((size_t)(b * 2048 + tt * 128 + tl)) * 6144 + 4096 + h * 128 + d0];
  }
  __syncthreads();
#pragma unroll 4
  for (int i = 0; i < 64; ++i) {
    int dd = i * 2 + t0;
    Vt[((size_t)(bh * 128 + dd)) * 2048 + tt * 128 + d0] = tile[d0][dd];
  }
}

// ---------------------------------------------------------------------------
// Flash attention, BQ=64, BK=64, 4 waves, balanced q-tile pairing:
// block handles q-tiles (31-pr) then (pr) -> 33 k-tiles per block.
// Pipelined: K/V double-buffered in LDS, prefetch next tile then
// s_waitcnt vmcnt(8) (counted, never 0 mid-loop), raw s_barrier only.
// Q fragments loaded directly from global. Block mapping puts all 16 pr
// of one (b,h) on one XCD -> K/V stay L2-resident (1 MB per bh).
// LDS 73 KB -> 2 blocks/CU.
// ---------------------------------------------------------------------------
#define SIG 0.1275174038536989f   // (1/sqrt(128)) * log2(e)

__global__ __launch_bounds__(256, 2) void attn_flash(
    const unsigned short* __restrict__ Q, const unsigned short* __restrict__ K,
    const unsigned short* __restrict__ Vt, unsigned short* __restrict__ Y) {
  __shared__ __align__(16) unsigned short Ks[2][64 * 128];
  __shared__ __align__(16) unsigned short Vs[2][128 * 64];
  __shared__ __align__(16) unsigned short Pl[64 * 72];   // P tile, stride 72

  const int x = blockIdx.x;
  const int bh = (x & 7) * 4 + ((x >> 3) & 3);   // same-bh blocks share an XCD
  const int pr = x >> 5;
  const int tid = threadIdx.x, w = tid >> 6, lane = tid & 63;
  const int r = lane & 15, q = lane >> 4;
  const int b = bh >> 4, h = bh & 15;
  const size_t kbase = (size_t)bh * 2048 * 128;
  const size_t vbase = (size_t)bh * 128 * 2048;
  const int vrow = lane >> 3, pc = lane & 7;

  for (int ph = 0; ph < 2; ++ph) {
    const int qt = ph ? pr : (31 - pr);

    // ---- Q fragments straight from global (16B/lane, no LDS round-trip)
    const size_t qbase = ((size_t)bh * 2048 + qt * 64) * 128;
    v8s qf[4];
#pragma unroll
    for (int ki = 0; ki < 4; ++ki)
      qf[ki] = *(const v8s*)&Q[qbase + (size_t)(w * 16 + r) * 128 +
                               (ki * 4 + q) * 8];

    float mrun[4], lrun[4];
    v4f O[8] = {};
#pragma unroll
    for (int p = 0; p < 4; ++p) { mrun[p] = -3.0e38f; lrun[p] = 0.f; }

    const int nkt = qt + 1;

    auto stageKV = [&](int kt, int buf) {
#pragma unroll
      for (int i = 0; i < 4; ++i) {
        const int key = w * 16 + i * 4 + q;
        const int gs = r ^ (key & 15);
        GL2LDS(K + kbase + ((size_t)kt * 64 + key) * 128 + gs * 8,
               &Ks[buf][(w * 16 + i * 4) * 128]);
      }
#pragma unroll
      for (int i = 0; i < 4; ++i) {
        const int d = w * 32 + i * 8 + vrow;
        const int gs = pc ^ (d & 7);
        GL2LDS(Vt + vbase + (size_t)d * 2048 + kt * 64 + gs * 8,
               &Vs[buf][(w * 32 + i * 8) * 64]);
      }
    };

    stageKV(0, 0);
    for (int kt = 0; kt < nkt; ++kt) {
      const int buf = kt & 1;
      if (kt + 1 < nkt) {
        stageKV(kt + 1, buf ^ 1);                       // prefetch next tile
        asm volatile("s_waitcnt vmcnt(8)" ::: "memory"); // tile kt resident
      } else {
        asm volatile("s_waitcnt vmcnt(0)" ::: "memory"); // no prefetch: drain
      }
      S_BARRIER();

      // ---- S = Q K^T  (rows: w*16 + q*4+p, cols: tn*16+r)
      v4f S[4] = {};
      __builtin_amdgcn_s_setprio(1);
#pragma unroll
      for (int ki = 0; ki < 4; ++ki) {
        v8s kf[4];
#pragma unroll
        for (int tn = 0; tn < 4; ++tn) {
          const int key = tn * 16 + r;
          const int c = (ki * 4 + q) ^ r;
          kf[tn] = *(const v8s*)&Ks[buf][key * 128 + c * 8];
        }
#pragma unroll
        for (int tn = 0; tn < 4; ++tn)
          S[tn] = __builtin_amdgcn_mfma_f32_16x16x32_bf16(
              qf[ki], kf[tn], S[tn], 0, 0, 0);
      }
      __builtin_amdgcn_s_setprio(0);

      // ---- causal mask (diagonal tile only: kt == qt)
      if (kt == qt) {
#pragma unroll
        for (int tn = 0; tn < 4; ++tn)
#pragma unroll
          for (int p = 0; p < 4; ++p) {
            const int tq = w * 16 + q * 4 + p;        // local q-row
            const int kg = tn * 16 + r;               // local key
            if (kg > tq) S[tn][p] = -3.0e38f;
          }
      }

      // ---- online softmax (base-2), P into S regs, rescale O
#pragma unroll
      for (int p = 0; p < 4; ++p) {
        float mx = fmaxf(fmaxf(S[0][p], S[1][p]), fmaxf(S[2][p], S[3][p]));
#pragma unroll
        for (int o = 1; o < 16; o <<= 1) mx = fmaxf(mx, __shfl_xor(mx, o, 64));
        const float mnew = fmaxf(mrun[p], mx);
        const float alpha = exp2f((mrun[p] - mnew) * SIG);
        mrun[p] = mnew;
        float sum = 0.f;
#pragma unroll
        for (int tn = 0; tn < 4; ++tn) {
          const float pv = exp2f((S[tn][p] - mnew) * SIG);
          S[tn][p] = pv;
          sum += pv;
        }
#pragma unroll
        for (int o = 1; o < 16; o <<= 1) sum += __shfl_xor(sum, o, 64);
        lrun[p] = lrun[p] * alpha + sum;
#pragma unroll
        for (int tn = 0; tn < 8; ++tn) O[tn][p] *= alpha;
      }

      // ---- P (bf16) to LDS, stride 72; wave-local rows only
#pragma unroll
      for (int tn = 0; tn < 4; ++tn)
#pragma unroll
        for (int p = 0; p < 4; ++p) {
          const int m = w * 16 + q * 4 + p;
          Pl[m * 72 + tn * 16 + r] = f2bf(S[tn][p]);
        }

      // ---- O += P V   (A=P rows, B=Vt rows)
      __builtin_amdgcn_s_setprio(1);
#pragma unroll
      for (int ki = 0; ki < 2; ++ki) {
        v8s pf, vf[8];
        const int m = w * 16 + r;
        pf = *(const v8s*)&Pl[m * 72 + (ki * 4 + q) * 8];
#pragma unroll
        for (int tn = 0; tn < 8; ++tn) {
          const int d = tn * 16 + r;
          const int c = (ki * 4 + q) ^ (d & 7);
          vf[tn] = *(const v8s*)&Vs[buf][d * 64 + c * 8];
        }
#pragma unroll
        for (int tn = 0; tn < 8; ++tn)
          O[tn] = __builtin_amdgcn_mfma_f32_16x16x32_bf16(
              pf, vf[tn], O[tn], 0, 0, 0);
      }
      __builtin_amdgcn_s_setprio(0);

      // all LDS reads of buf retired (every ds_read feeds an MFMA above);
      // belt-and-braces lgkm drain, then barrier frees buf for restaging.
      asm volatile("s_waitcnt lgkmcnt(0)" ::: "memory");
      S_BARRIER();
    }

    // ---- epilogue: O/l -> Y[(b*T+t)][h*128+d]
#pragma unroll
    for (int p = 0; p < 4; ++p) {
      const float inv = 1.0f / lrun[p];
      const int t = qt * 64 + w * 16 + q * 4 + p;
#pragma unroll
      for (int tn = 0; tn < 8; ++tn)
        Y[((size_t)(b * 2048 + t)) * 2048 + h * 128 + tn * 16 + r] =
            f2bf(O[tn][p] * inv);
    }
  }
}

// ---------------------------------------------------------------------------
// Launch
// ---------------------------------------------------------------------------
extern "C" void kernel_launch(void* const* d_in, const int* in_sizes, int n_in,
                              void* d_out, int out_size, void* d_ws, size_t ws_size,
                              hipStream_t stream) {
  const float* x_a   = (const float*)d_in[0];
  const float* x_b   = (const float*)d_in[1];
  const float* cosb  = (const float*)d_in[2];
  const float* sinb  = (const float*)d_in[3];
  const float* Wqkv_a  = (const float*)d_in[5];
  const float* Wqkv_b  = (const float*)d_in[6];
  const float* Wproj_a = (const float*)d_in[7];
  const float* Wproj_b = (const float*)d_in[8];
  float* out = (float*)d_out;

  if (ws_size < 100663296u) return;

  char* ws = (char*)d_ws;
  unsigned short* QKVall = (unsigned short*)(ws);                // [0,48M)
  unsigned short* XA     = (unsigned short*)(ws + 50331648);     // [48,56M)
  unsigned short* WQT    = (unsigned short*)(ws + 67108864);     // [64,88M)
  unsigned short* Qb     = (unsigned short*)(ws + 50331648);     // [48,64M)
  unsigned short* Kb     = (unsigned short*)(ws + 67108864);     // [64,80M)
  unsigned short* Vtb    = (unsigned short*)(ws + 83886080);     // [80,96M)
  unsigned short* Yb     = (unsigned short*)(ws);                // [0,16M)
  unsigned short* WPT_A  = (unsigned short*)(ws + 16777216);     // [16,24M)
  unsigned short* WPT_B  = (unsigned short*)(ws + 25165824);     // [24,32M)

  // phase 1: conversions + qkv GEMMs (token-scattered output rows)
  hipLaunchKernelGGL(f32_to_bf16_2, dim3(8192), dim3(256), 0, stream,
                     (const float4*)x_a, (const float4*)x_b, (uint2*)XA, 1048576);
  hipLaunchKernelGGL(transpose_f32_bf16, dim3(96, 32, 1), dim3(256), 0, stream,
                     Wqkv_a, Wqkv_a, WQT, WQT, 2048, 6144);
  hipLaunchKernelGGL((gemm256<0, 1>), dim3(192, 1), dim3(512), 0, stream,
                     XA, WQT, WQT, QKVall, 2048, 6144, 2048, 24);
  hipLaunchKernelGGL(transpose_f32_bf16, dim3(96, 32, 1), dim3(256), 0, stream,
                     Wqkv_b, Wqkv_b, WQT, WQT, 2048, 6144);
  hipLaunchKernelGGL((gemm256<0, 2>), dim3(192, 1), dim3(512), 0, stream,
                     XA + (size_t)4194304, WQT, WQT, QKVall, 2048, 6144, 2048, 24);

  // phase 2: RoPE Q/K + V transpose (both read QKVall)
  hipLaunchKernelGGL(scatter_rope, dim3(4096), dim3(256), 0, stream,
                     QKVall, cosb, sinb, Qb, Kb);
  hipLaunchKernelGGL(transpose_v, dim3(512), dim3(256), 0, stream,
                     QKVall, Vtb);

  // phase 3: both Wproj transposes in one launch (dead QKVall region)
  hipLaunchKernelGGL(transpose_f32_bf16, dim3(32, 32, 2), dim3(256), 0, stream,
                     Wproj_a, Wproj_b, WPT_A, WPT_B, 2048, 2048);

  // phase 4: flash attention -> Yb (balanced q-tile pairs)
  hipLaunchKernelGGL(attn_flash, dim3(512), dim3(256), 0, stream,
                     Qb, Kb, Vtb, Yb);

  // phase 5: both output projections in one launch (y = stream parity)
  hipLaunchKernelGGL((gemm256<1, 0>), dim3(64, 2), dim3(512), 0, stream,
                     Yb, WPT_A, WPT_B, out, 2048, 2048, 2048, 8);
}